// Round 8
// baseline (357.669 us; speedup 1.0000x reference)
//
#include <hip/hip_runtime.h>

typedef unsigned short u16;
typedef __attribute__((ext_vector_type(8))) short bf8;    // 8 x bf16 MFMA fragment
typedef __attribute__((ext_vector_type(4))) short s16x4;
typedef __attribute__((ext_vector_type(4))) float f32x4;
typedef __attribute__((ext_vector_type(4))) int   i32x4;

#define S_   96
#define T_   50
#define NSEQ 1536
#define NR   1537
#define ZR   1537   // sentinel zero-row index (gi/gh/hf have NR+1 rows)
#define XROW 520    // LDS row stride in shorts: 1040 B, 16B-aligned
// hidden width 256, gate width 768

__device__ __forceinline__ float bf2f(u16 u){ return __uint_as_float(((unsigned)u)<<16); }
__device__ __forceinline__ u16 f2bf(float f){
  unsigned u = __float_as_uint(f);
  u += 0x7fffu + ((u>>16)&1u);           // RNE
  return (u16)(u>>16);
}
// division-free; fine vs 2% threshold, NaN-safe at +-inf
__device__ __forceinline__ float sigm(float x){
  return __builtin_amdgcn_rcpf(1.f + __expf(-x));
}
__device__ __forceinline__ float tanh_(float x){
  return 1.f - 2.f*__builtin_amdgcn_rcpf(__expf(2.f*x) + 1.f);
}
// barrier that drains only LDS (lgkm), NOT in-flight global prefetch (vmcnt).
__device__ __forceinline__ void bar_lds(){
  asm volatile("s_waitcnt lgkmcnt(0)\n\ts_barrier" ::: "memory");
}

// ---------------------------------------------------------------------------
// Stage 0 (fused): blocks [0,1088) convert fp32 weights to bf16 (LSTM weights
// row-permuted); blocks [1088, 1088+NSEQ) build compacted active-partner
// lists PADDED to a multiple of 4 with (ZR,ZR) sentinels; the last block
// zeroes row ZR of gi/gh/hf0/hf1 (sentinel GRU contributes exactly 0).
// ---------------------------------------------------------------------------
struct CvtArgs { const float* s[10]; u16* d[10]; };
__global__ __launch_bounds__(256) void prep_kernel(CvtArgs a,
    const int* __restrict__ par, const int* __restrict__ chi,
    const float* __restrict__ mask,
    int2* __restrict__ ent0, int* __restrict__ cnt0,
    int2* __restrict__ ent1, int* __restrict__ cnt1,
    u16* __restrict__ gi, u16* __restrict__ gh,
    float* __restrict__ hf0, float* __restrict__ hf1)
{
  if (blockIdx.x < 1088){
    int e = (blockIdx.x*256 + threadIdx.x)*4;
    if (e >= 1114112) return;
    int t, off;
    if (e < 262144){ t = e>>16; off = e & 65535; }
    else if (e < 327680){ int e2=e-262144; t = 4+(e2>>15); off = e2&32767; }
    else { int e3=e-327680; t = 6 + e3/196608; off = e3%196608; }
    int src = off;
    if (t < 4){
      int colp = off>>7, k = off&127;
      int orig = ((colp>>4)&3)*128 + ((colp>>6)<<4) + (colp&15);
      src = orig*128 + k;
    }
    f32x4 v = *reinterpret_cast<const f32x4*>(a.s[t]+src);
    s16x4 o;
    #pragma unroll
    for (int i=0;i<4;i++) o[i]=(short)f2bf(v[i]);
    *reinterpret_cast<s16x4*>(a.d[t]+off) = o;
  } else if (blockIdx.x < 1088 + NSEQ){
    const int rr = blockIdx.x - 1088;
    __shared__ int c0s, c1s;
    if (threadIdx.x==0){ c0s=0; c1s=0; }
    __syncthreads();
    const int l = threadIdx.x;
    if (l < S_){
      const int b = rr/S_, fx = rr%S_, base = b*S_*S_;
      int idx = base + l*S_ + fx;
      if (mask[idx] != 0.f){
        int p = atomicAdd(&c0s, 1);
        ent0[rr*S_ + p] = make_int2(chi[idx], par[idx]);
      }
      int jdx = base + fx*S_ + l;
      if (mask[jdx] != 0.f){
        int p = atomicAdd(&c1s, 1);
        ent1[rr*S_ + p] = make_int2(par[jdx], chi[jdx]);
      }
    }
    __syncthreads();
    const int c0 = c0s, c1 = c1s;
    const int c0p = (c0+3)&~3, c1p = (c1+3)&~3;
    if (l >= c0 && l < c0p) ent0[rr*S_ + l] = make_int2(ZR, ZR);
    if (l >= c1 && l < c1p) ent1[rr*S_ + l] = make_int2(ZR, ZR);
    if (threadIdx.x==0){ cnt0[rr]=c0p; cnt1[rr]=c1p; }
  } else {
    // zero sentinel rows
    const int l = threadIdx.x;
    for (int i=l; i<768; i+=256){ gi[ZR*768+i]=0; gh[ZR*768+i]=0; }
    if (l < 256){ hf0[ZR*256+l]=0.f; hf1[ZR*256+l]=0.f; }
  }
}

// ---------------------------------------------------------------------------
// Stage 1: bidirectional LSTM final states (unchanged from round 6).
// ---------------------------------------------------------------------------
__global__ __launch_bounds__(512, 2) void lstm_kernel(
    const int* __restrict__ enc, const float* __restrict__ emb,
    const u16* __restrict__ WihF, const u16* __restrict__ WhhF, const float* __restrict__ bF,
    const u16* __restrict__ WihB, const u16* __restrict__ WhhB, const float* __restrict__ bB,
    u16* __restrict__ c_cat, u16* __restrict__ h_cat)
{
  __shared__ short xh[16*XROW];
  __shared__ int   toks[16*T_];

  const int tid  = threadIdx.x;
  const int wave = tid>>6;
  const int lane = tid&63;
  const int dir  = blockIdx.y;
  const int s0   = blockIdx.x*16;

  const u16* Wih = dir ? WihB : WihF;
  const u16* Whh = dir ? WhhB : WhhF;
  const float* bb = dir ? bB  : bF;

  for (int i=tid; i<16*T_; i+=512)
    toks[i] = enc[(s0 + i/T_)*T_ + (i%T_)];

  const int mL   = lane&15;
  const int quad = lane>>4;
  const int kb   = quad*8;

  bf8 Breg[4][8];
  f32x4 bias4[4];
  #pragma unroll
  for (int n=0;n<4;n++){
    int colp = wave*64 + n*16 + mL;
    bias4[n] = *reinterpret_cast<const f32x4*>(bb + n*128 + wave*16 + quad*4);
    #pragma unroll
    for (int ks=0;ks<8;ks++){
      int k = ks*32 + kb;
      const u16* p = (k<128) ? (Wih + colp*128 + k) : (Whh + colp*128 + (k-128));
      Breg[n][ks] = *reinterpret_cast<const bf8*>(p);
      asm volatile("" : "+v"(Breg[n][ks]));
    }
  }

  if (tid<256){
    int r = tid>>4, c = tid&15;
    *reinterpret_cast<i32x4*>(&xh[r*XROW + 256 + c*8]) = (i32x4){0,0,0,0};
  }

  const int srow = tid>>5, schunk = tid&31;
  float cst[4] = {0.f,0.f,0.f,0.f};
  float hst[4] = {0.f,0.f,0.f,0.f};

  __syncthreads();

  {
    int tok = toks[srow*T_ + (dir ? (T_-1) : 0)];
    f32x4 xv = *reinterpret_cast<const f32x4*>(emb + tok*128 + schunk*4);
    s16x4 xp;
    #pragma unroll
    for (int i=0;i<4;i++) xp[i]=(short)f2bf(xv[i]);
    *reinterpret_cast<s16x4*>(&xh[srow*XROW + schunk*4]) = xp;
  }
  f32x4 xv1, xv2;
  {
    int tok1 = toks[srow*T_ + (dir ? (T_-2) : 1)];
    xv1 = *reinterpret_cast<const f32x4*>(emb + tok1*128 + schunk*4);
    int tok2 = toks[srow*T_ + (dir ? (T_-3) : 2)];
    xv2 = *reinterpret_cast<const f32x4*>(emb + tok2*128 + schunk*4);
  }
  __syncthreads();

  for (int t=0;t<T_;t++){
    const int cb = t&1, nb2 = (t+1)&1;
    if (t+1 < T_){
      s16x4 xp;
      #pragma unroll
      for (int i=0;i<4;i++) xp[i]=(short)f2bf(xv1[i]);
      *reinterpret_cast<s16x4*>(&xh[srow*XROW + nb2*128 + schunk*4]) = xp;
    }
    xv1 = xv2;
    if (t+3 < T_){
      int tok = toks[srow*T_ + (dir ? (T_-4-t) : (t+3))];
      xv2 = *reinterpret_cast<const f32x4*>(emb + tok*128 + schunk*4);
    }

    f32x4 acc[4];
    #pragma unroll
    for (int i=0;i<4;i++) acc[i] = (f32x4){0.f,0.f,0.f,0.f};
    #pragma unroll
    for (int ks=0;ks<8;ks++){
      int k = ks*32 + kb;
      int off = (k<128) ? (cb*128 + k) : (256 + cb*128 + (k-128));
      bf8 b = *reinterpret_cast<const bf8*>(&xh[mL*XROW + off]);
      #pragma unroll
      for (int n=0;n<4;n++)
        acc[n] = __builtin_amdgcn_mfma_f32_16x16x32_bf16(Breg[n][ks], b, acc[n], 0,0,0);
    }

    s16x4 hp;
    #pragma unroll
    for (int i=0;i<4;i++){
      float gi_ = acc[0][i]+bias4[0][i];
      float gf_ = acc[1][i]+bias4[1][i];
      float gg_ = acc[2][i]+bias4[2][i];
      float go_ = acc[3][i]+bias4[3][i];
      float c = sigm(gf_)*cst[i] + sigm(gi_)*tanh_(gg_);
      float h = sigm(go_)*tanh_(c);
      cst[i]=c; hst[i]=h;
      hp[i] = (short)f2bf(h);
    }
    *reinterpret_cast<s16x4*>(&xh[mL*XROW + 256 + nb2*128 + wave*16 + quad*4]) = hp;
    bar_lds();
  }

  {
    const int ch = wave*16 + quad*4;
    const int gs = s0 + mL;
    s16x4 cp_, hp_;
    #pragma unroll
    for (int i=0;i<4;i++){ cp_[i]=(short)f2bf(cst[i]); hp_[i]=(short)f2bf(hst[i]); }
    *reinterpret_cast<s16x4*>(c_cat + gs*256 + dir*128 + ch) = cp_;
    *reinterpret_cast<s16x4*>(h_cat + gs*256 + dir*128 + ch) = hp_;
  }
}

// ---------------------------------------------------------------------------
// Stage 2: hidden = [relu(cc@Wc.T+bc) | relu(hc@Whr.T+bhr)], row 0 zeroed.
// ---------------------------------------------------------------------------
__global__ __launch_bounds__(256) void reduce_kernel(
    const u16* __restrict__ c_cat, const u16* __restrict__ h_cat,
    const u16* __restrict__ Wc, const float* __restrict__ bc,
    const u16* __restrict__ Whr, const float* __restrict__ bhr,
    float* __restrict__ hidf, u16* __restrict__ hidb)
{
  const int tid=threadIdx.x, wave=tid>>6, lane=tid&63;
  const int mL=lane&15, quad=lane>>4, kb=quad*8;
  const int m0 = blockIdx.x*64;
  const u16* A    = (wave<2) ? c_cat : h_cat;
  const u16* W    = (wave<2) ? Wc  : Whr;
  const float* bv = (wave<2) ? bc  : bhr;
  const int nb    = (wave&1)*64;
  const int obase = (wave<2) ? 0 : 128;

  f32x4 acc[4][4];
  #pragma unroll
  for (int mt=0;mt<4;mt++)
    #pragma unroll
    for (int nt=0;nt<4;nt++) acc[mt][nt] = (f32x4){0.f,0.f,0.f,0.f};

  #pragma unroll
  for (int ks=0;ks<8;ks++){
    int k = ks*32 + kb;
    bf8 bfr[4];
    #pragma unroll
    for (int nt=0;nt<4;nt++)
      bfr[nt] = *reinterpret_cast<const bf8*>(W + (nb+nt*16+mL)*256 + k);
    #pragma unroll
    for (int mt=0;mt<4;mt++){
      bf8 a = *reinterpret_cast<const bf8*>(A + (m0+mt*16+mL)*256 + k);
      #pragma unroll
      for (int nt=0;nt<4;nt++)
        acc[mt][nt] = __builtin_amdgcn_mfma_f32_16x16x32_bf16(a, bfr[nt], acc[mt][nt], 0,0,0);
    }
  }
  const int row0 = quad*4;
  float biasv[4];
  #pragma unroll
  for (int nt=0;nt<4;nt++) biasv[nt] = bv[nb+nt*16+mL];
  #pragma unroll
  for (int mt=0;mt<4;mt++){
    #pragma unroll
    for (int nt=0;nt<4;nt++){
      int col = obase + nb + nt*16 + mL;
      #pragma unroll
      for (int i=0;i<4;i++){
        int r = m0 + mt*16 + row0 + i;
        float v = fmaxf(acc[mt][nt][i] + biasv[nt], 0.f);
        hidf[(r+1)*256 + col] = v;
        hidb[(r+1)*256 + col] = f2bf(v);
      }
    }
  }
  if (blockIdx.x==0 && tid<64){
    #pragma unroll
    for (int j=0;j<4;j++){ hidf[tid*4+j] = 0.f; hidb[tid*4+j] = 0; }
  }
}

// ---------------------------------------------------------------------------
// Stage 3 (x4): gi = hidden@Wi.T + bi, gh = hidden@Wh.T + bh  (bf16 tables)
// ---------------------------------------------------------------------------
__global__ __launch_bounds__(256) void gates_gemm_kernel(
    const u16* __restrict__ hidb,
    const u16* __restrict__ Wi, const u16* __restrict__ Wh,
    const float* __restrict__ bi, const float* __restrict__ bh,
    u16* __restrict__ gi, u16* __restrict__ gh)
{
  const int tid=threadIdx.x, wave=tid>>6, lane=tid&63;
  const int mL=lane&15, quad=lane>>4, kb=quad*8;
  const int m0 = blockIdx.x*32;
  const int n0 = blockIdx.y*256 + wave*64;
  const bool isI = (n0 < 768);
  const u16* W    = isI ? Wi : Wh;
  const float* bv = isI ? bi : bh;
  u16* out        = isI ? gi : gh;
  const int nbc   = isI ? n0 : (n0-768);

  int arow[2];
  #pragma unroll
  for (int mt=0;mt<2;mt++) arow[mt] = min(m0+mt*16+mL, NR-1);

  f32x4 acc[2][4];
  #pragma unroll
  for (int mt=0;mt<2;mt++)
    #pragma unroll
    for (int nt=0;nt<4;nt++) acc[mt][nt] = (f32x4){0.f,0.f,0.f,0.f};

  #pragma unroll
  for (int ks=0;ks<8;ks++){
    int k = ks*32 + kb;
    bf8 bfr[4];
    #pragma unroll
    for (int nt=0;nt<4;nt++)
      bfr[nt] = *reinterpret_cast<const bf8*>(W + (nbc+nt*16+mL)*256 + k);
    #pragma unroll
    for (int mt=0;mt<2;mt++){
      bf8 a = *reinterpret_cast<const bf8*>(hidb + arow[mt]*256 + k);
      #pragma unroll
      for (int nt=0;nt<4;nt++)
        acc[mt][nt] = __builtin_amdgcn_mfma_f32_16x16x32_bf16(a, bfr[nt], acc[mt][nt], 0,0,0);
    }
  }
  const int row0 = quad*4;
  float biasv[4];
  #pragma unroll
  for (int nt=0;nt<4;nt++) biasv[nt] = bv[nbc+nt*16+mL];
  #pragma unroll
  for (int mt=0;mt<2;mt++){
    #pragma unroll
    for (int nt=0;nt<4;nt++){
      #pragma unroll
      for (int i=0;i<4;i++){
        int r = m0 + mt*16 + row0 + i;
        if (r < NR)
          out[r*768 + nbc + nt*16 + mL] = f2bf(acc[mt][nt][i] + biasv[nt]);
      }
    }
  }
}

// ---------------------------------------------------------------------------
// Stage 4 (x4): one wave per output row; lists padded to multiple of 4 ->
// fixed unroll-by-4 groups: 28 independent loads in flight per group.
// Norm = pure 64-lane shuffle reduction. No LDS, no barriers.
// ---------------------------------------------------------------------------
__global__ __launch_bounds__(256) void pair_kernel(
    const u16* __restrict__ gi, const u16* __restrict__ gh,
    const float* __restrict__ hin,
    float* __restrict__ hout, u16* __restrict__ bout, float* __restrict__ dout,
    const int2* __restrict__ ent, const int* __restrict__ cnt)
{
  const int row  = blockIdx.x*4 + (threadIdx.x>>6);
  const int lane = threadIdx.x & 63;
  if (row >= NR) return;
  const int ch0 = lane*4;
  if (row == 0){
    f32x4 z = {0.f,0.f,0.f,0.f};
    s16x4 zb = {0,0,0,0};
    *reinterpret_cast<f32x4*>(hout + ch0) = z;
    *reinterpret_cast<s16x4*>(bout + ch0) = zb;
    if (dout) *reinterpret_cast<f32x4*>(dout + ch0) = z;
    return;
  }
  const int rr = row - 1;
  const int n4 = cnt[rr];              // padded to multiple of 4
  const int2* e = ent + rr*S_;

  float aa[4] = {0.f,0.f,0.f,0.f};
  if (n4 <= 64){
    int2 eA = e[lane];
    for (int k=0; k<n4; k+=4){
      int xs[4], hs[4];
      #pragma unroll
      for (int j=0;j<4;j++){
        xs[j] = __shfl(eA.x, k+j, 64);
        hs[j] = __shfl(eA.y, k+j, 64);
      }
      s16x4 vi0[4],vi1[4],vi2[4],vh0[4],vh1[4],vh2[4];
      f32x4 hv[4];
      #pragma unroll
      for (int j=0;j<4;j++){
        const u16* gx = gi + xs[j]*768 + ch0;
        const u16* gy = gh + hs[j]*768 + ch0;
        vi0[j] = *reinterpret_cast<const s16x4*>(gx);
        vi1[j] = *reinterpret_cast<const s16x4*>(gx+256);
        vi2[j] = *reinterpret_cast<const s16x4*>(gx+512);
        vh0[j] = *reinterpret_cast<const s16x4*>(gy);
        vh1[j] = *reinterpret_cast<const s16x4*>(gy+256);
        vh2[j] = *reinterpret_cast<const s16x4*>(gy+512);
        hv[j]  = *reinterpret_cast<const f32x4*>(hin + hs[j]*256 + ch0);
      }
      #pragma unroll
      for (int j=0;j<4;j++){
        #pragma unroll
        for (int i=0;i<4;i++){
          float rg = sigm(bf2f((u16)vi0[j][i]) + bf2f((u16)vh0[j][i]));
          float zg = sigm(bf2f((u16)vi1[j][i]) + bf2f((u16)vh1[j][i]));
          float ng = tanh_(bf2f((u16)vi2[j][i]) + rg*bf2f((u16)vh2[j][i]));
          aa[i] += (1.f-zg)*ng + zg*hv[j][i];
        }
      }
    }
  } else {
    // rare fallback (n > 64): simple scalar loop
    for (int k=0; k<n4; k++){
      int2 pr = e[k];
      const u16* gx = gi + pr.x*768 + ch0;
      const u16* gy = gh + pr.y*768 + ch0;
      s16x4 vi0 = *reinterpret_cast<const s16x4*>(gx);
      s16x4 vi1 = *reinterpret_cast<const s16x4*>(gx+256);
      s16x4 vi2 = *reinterpret_cast<const s16x4*>(gx+512);
      s16x4 vh0 = *reinterpret_cast<const s16x4*>(gy);
      s16x4 vh1 = *reinterpret_cast<const s16x4*>(gy+256);
      s16x4 vh2 = *reinterpret_cast<const s16x4*>(gy+512);
      f32x4 hv  = *reinterpret_cast<const f32x4*>(hin + pr.y*256 + ch0);
      #pragma unroll
      for (int i=0;i<4;i++){
        float rg = sigm(bf2f((u16)vi0[i]) + bf2f((u16)vh0[i]));
        float zg = sigm(bf2f((u16)vi1[i]) + bf2f((u16)vh1[i]));
        float ng = tanh_(bf2f((u16)vi2[i]) + rg*bf2f((u16)vh2[i]));
        aa[i] += (1.f-zg)*ng + zg*hv[i];
      }
    }
  }

  float sq = aa[0]*aa[0] + aa[1]*aa[1] + aa[2]*aa[2] + aa[3]*aa[3];
  #pragma unroll
  for (int off=32; off>0; off>>=1) sq += __shfl_xor(sq, off, 64);
  float v  = sqrtf(sq);
  float sc = (v + 0.25f)*__builtin_amdgcn_rcpf(v + 1.f);

  f32x4 hv = *reinterpret_cast<const f32x4*>(hin + row*256 + ch0);
  f32x4 nv = { hv[0]+aa[0]*sc, hv[1]+aa[1]*sc, hv[2]+aa[2]*sc, hv[3]+aa[3]*sc };
  *reinterpret_cast<f32x4*>(hout + row*256 + ch0) = nv;
  s16x4 nb;
  #pragma unroll
  for (int i=0;i<4;i++) nb[i] = (short)f2bf(nv[i]);
  *reinterpret_cast<s16x4*>(bout + row*256 + ch0) = nb;
  if (dout) *reinterpret_cast<f32x4*>(dout + row*256 + ch0) = nv;
}

// ---------------------------------------------------------------------------
extern "C" void kernel_launch(void* const* d_in, const int* in_sizes, int n_in,
                              void* d_out, int out_size, void* d_ws, size_t ws_size,
                              hipStream_t stream)
{
  const int*   enc  = (const int*)  d_in[0];
  const int*   spar = (const int*)  d_in[1];
  const int*   schi = (const int*)  d_in[2];
  const float* mask = (const float*)d_in[3];
  const float* emb  = (const float*)d_in[4];
  const float* WihF = (const float*)d_in[5];
  const float* WhhF = (const float*)d_in[6];
  const float* bF   = (const float*)d_in[7];
  const float* WihB = (const float*)d_in[8];
  const float* WhhB = (const float*)d_in[9];
  const float* bB   = (const float*)d_in[10];
  const float* Wc   = (const float*)d_in[11];
  const float* bc   = (const float*)d_in[12];
  const float* Whr  = (const float*)d_in[13];
  const float* bhr  = (const float*)d_in[14];
  const float* WiCP = (const float*)d_in[15];
  const float* WhCP = (const float*)d_in[16];
  const float* biCP = (const float*)d_in[17];
  const float* bhCP = (const float*)d_in[18];
  const float* WiPC = (const float*)d_in[19];
  const float* WhPC = (const float*)d_in[20];
  const float* biPC = (const float*)d_in[21];
  const float* bhPC = (const float*)d_in[22];

  // workspace layout (~14.8 MB); hf/gi/gh have NR+1 rows (sentinel row ZR)
  char* ws = (char*)d_ws;
  u16*   c_cat = (u16*)  (ws + 0);          // 1536*256 bf16
  u16*   h_cat = (u16*)  (ws + 786432);
  float* hf0   = (float*)(ws + 1572864);    // 1538*256 f32
  float* hf1   = (float*)(ws + 3148800);    // 1538*256 f32
  u16*   hb    = (u16*)  (ws + 4724736);    // 1537*256 bf16
  u16*   gi    = (u16*)  (ws + 5511680);    // 1538*768 bf16
  u16*   gh    = (u16*)  (ws + 7874048);
  u16*   wbf   = (u16*)  (ws + 10236416);   // bf16 weights (1114112 elems)
  int2*  ent0  = (int2*) (ws + 12464640);   // 1536*96 int2
  int2*  ent1  = (int2*) (ws + 13644288);
  int*   cnt0  = (int*)  (ws + 14823936);
  int*   cnt1  = (int*)  (ws + 14830080);
  float* out   = (float*)d_out;

  u16* bWihF = wbf + 0;
  u16* bWhhF = wbf + 65536;
  u16* bWihB = wbf + 131072;
  u16* bWhhB = wbf + 196608;
  u16* bWc   = wbf + 262144;
  u16* bWhr  = wbf + 294912;
  u16* bWiCP = wbf + 327680;
  u16* bWhCP = wbf + 524288;
  u16* bWiPC = wbf + 720896;
  u16* bWhPC = wbf + 917504;

  CvtArgs ca;
  ca.s[0]=WihF; ca.s[1]=WhhF; ca.s[2]=WihB; ca.s[3]=WhhB;
  ca.s[4]=Wc;   ca.s[5]=Whr;
  ca.s[6]=WiCP; ca.s[7]=WhCP; ca.s[8]=WiPC; ca.s[9]=WhPC;
  ca.d[0]=bWihF; ca.d[1]=bWhhF; ca.d[2]=bWihB; ca.d[3]=bWhhB;
  ca.d[4]=bWc;   ca.d[5]=bWhr;
  ca.d[6]=bWiCP; ca.d[7]=bWhCP; ca.d[8]=bWiPC; ca.d[9]=bWhPC;
  prep_kernel<<<dim3(1088+NSEQ+1), dim3(256), 0, stream>>>(
      ca, spar, schi, mask, ent0, cnt0, ent1, cnt1, gi, gh, hf0, hf1);

  lstm_kernel<<<dim3(96,2), dim3(512), 0, stream>>>(
      enc, emb, bWihF,bWhhF,bF, bWihB,bWhhB,bB, c_cat, h_cat);
  reduce_kernel<<<dim3(24), dim3(256), 0, stream>>>(
      c_cat,h_cat, bWc,bc,bWhr,bhr, hf0,hb);

  float* hfb[2] = {hf0,hf1};
  int cur = 0;
  for (int it=0; it<4; it++){
    const u16* Wi   = (it<2)?bWiCP:bWiPC;
    const u16* Wh   = (it<2)?bWhCP:bWhPC;
    const float* bi = (it<2)?biCP:biPC;
    const float* bh = (it<2)?bhCP:bhPC;
    int nxt = cur^1;
    gates_gemm_kernel<<<dim3(49,6), dim3(256), 0, stream>>>(
        hb, Wi,Wh,bi,bh, gi,gh);
    pair_kernel<<<dim3((NR+3)/4), dim3(256), 0, stream>>>(
        gi,gh, hfb[cur], hfb[nxt], hb,
        (it==3)?out:(float*)nullptr,
        (it<2)?ent0:ent1, (it<2)?cnt0:cnt1);
    cur = nxt;
  }
}

// Round 9
// 332.163 us; speedup vs baseline: 1.0768x; 1.0768x over previous
//
#include <hip/hip_runtime.h>

typedef unsigned short u16;
typedef __attribute__((ext_vector_type(8))) short bf8;    // 8 x bf16 MFMA fragment
typedef __attribute__((ext_vector_type(4))) short s16x4;
typedef __attribute__((ext_vector_type(4))) float f32x4;
typedef __attribute__((ext_vector_type(4))) int   i32x4;

#define S_   96
#define T_   50
#define NSEQ 1536
#define NR   1537
#define ZR   1537   // sentinel zero-row index (gi/gh/hf have NR+1 rows)
#define XROW 520    // LDS row stride in shorts: 1040 B, 16B-aligned
// hidden width 256, gate width 768

__device__ __forceinline__ float bf2f(u16 u){ return __uint_as_float(((unsigned)u)<<16); }
__device__ __forceinline__ u16 f2bf(float f){
  unsigned u = __float_as_uint(f);
  u += 0x7fffu + ((u>>16)&1u);           // RNE
  return (u16)(u>>16);
}
// division-free; fine vs 2% threshold, NaN-safe at +-inf
__device__ __forceinline__ float sigm(float x){
  return __builtin_amdgcn_rcpf(1.f + __expf(-x));
}
__device__ __forceinline__ float tanh_(float x){
  return 1.f - 2.f*__builtin_amdgcn_rcpf(__expf(2.f*x) + 1.f);
}
// barrier that drains only LDS (lgkm), NOT in-flight global prefetch (vmcnt).
__device__ __forceinline__ void bar_lds(){
  asm volatile("s_waitcnt lgkmcnt(0)\n\ts_barrier" ::: "memory");
}

// ---------------------------------------------------------------------------
// Stage 0 (fused): blocks [0,1088) convert fp32 weights to bf16 (LSTM weights
// row-permuted); blocks [1088, 1088+NSEQ) build compacted active-partner
// lists PADDED to a multiple of 4 with (ZR,ZR) sentinels; the last block
// zeroes row ZR of gi/gh/hf0/hf1 (sentinel GRU contributes exactly 0).
// ---------------------------------------------------------------------------
struct CvtArgs { const float* s[10]; u16* d[10]; };
__global__ __launch_bounds__(256) void prep_kernel(CvtArgs a,
    const int* __restrict__ par, const int* __restrict__ chi,
    const float* __restrict__ mask,
    int2* __restrict__ ent0, int* __restrict__ cnt0,
    int2* __restrict__ ent1, int* __restrict__ cnt1,
    u16* __restrict__ gi, u16* __restrict__ gh,
    float* __restrict__ hf0, float* __restrict__ hf1)
{
  if (blockIdx.x < 1088){
    int e = (blockIdx.x*256 + threadIdx.x)*4;
    if (e >= 1114112) return;
    int t, off;
    if (e < 262144){ t = e>>16; off = e & 65535; }
    else if (e < 327680){ int e2=e-262144; t = 4+(e2>>15); off = e2&32767; }
    else { int e3=e-327680; t = 6 + e3/196608; off = e3%196608; }
    int src = off;
    if (t < 4){
      int colp = off>>7, k = off&127;
      int orig = ((colp>>4)&3)*128 + ((colp>>6)<<4) + (colp&15);
      src = orig*128 + k;
    }
    f32x4 v = *reinterpret_cast<const f32x4*>(a.s[t]+src);
    s16x4 o;
    #pragma unroll
    for (int i=0;i<4;i++) o[i]=(short)f2bf(v[i]);
    *reinterpret_cast<s16x4*>(a.d[t]+off) = o;
  } else if (blockIdx.x < 1088 + NSEQ){
    const int rr = blockIdx.x - 1088;
    __shared__ int c0s, c1s;
    if (threadIdx.x==0){ c0s=0; c1s=0; }
    __syncthreads();
    const int l = threadIdx.x;
    if (l < S_){
      const int b = rr/S_, fx = rr%S_, base = b*S_*S_;
      int idx = base + l*S_ + fx;
      if (mask[idx] != 0.f){
        int p = atomicAdd(&c0s, 1);
        ent0[rr*S_ + p] = make_int2(chi[idx], par[idx]);
      }
      int jdx = base + fx*S_ + l;
      if (mask[jdx] != 0.f){
        int p = atomicAdd(&c1s, 1);
        ent1[rr*S_ + p] = make_int2(par[jdx], chi[jdx]);
      }
    }
    __syncthreads();
    const int c0 = c0s, c1 = c1s;
    const int c0p = (c0+3)&~3, c1p = (c1+3)&~3;
    if (l >= c0 && l < c0p) ent0[rr*S_ + l] = make_int2(ZR, ZR);
    if (l >= c1 && l < c1p) ent1[rr*S_ + l] = make_int2(ZR, ZR);
    if (threadIdx.x==0){ cnt0[rr]=c0p; cnt1[rr]=c1p; }
  } else {
    // zero sentinel rows
    const int l = threadIdx.x;
    for (int i=l; i<768; i+=256){ gi[ZR*768+i]=0; gh[ZR*768+i]=0; }
    if (l < 256){ hf0[ZR*256+l]=0.f; hf1[ZR*256+l]=0.f; }
  }
}

// ---------------------------------------------------------------------------
// Stage 1: bidirectional LSTM final states (round-6 structure, unchanged).
// ---------------------------------------------------------------------------
__global__ __launch_bounds__(512, 2) void lstm_kernel(
    const int* __restrict__ enc, const float* __restrict__ emb,
    const u16* __restrict__ WihF, const u16* __restrict__ WhhF, const float* __restrict__ bF,
    const u16* __restrict__ WihB, const u16* __restrict__ WhhB, const float* __restrict__ bB,
    u16* __restrict__ c_cat, u16* __restrict__ h_cat)
{
  __shared__ short xh[16*XROW];
  __shared__ int   toks[16*T_];

  const int tid  = threadIdx.x;
  const int wave = tid>>6;
  const int lane = tid&63;
  const int dir  = blockIdx.y;
  const int s0   = blockIdx.x*16;

  const u16* Wih = dir ? WihB : WihF;
  const u16* Whh = dir ? WhhB : WhhF;
  const float* bb = dir ? bB  : bF;

  for (int i=tid; i<16*T_; i+=512)
    toks[i] = enc[(s0 + i/T_)*T_ + (i%T_)];

  const int mL   = lane&15;
  const int quad = lane>>4;
  const int kb   = quad*8;

  bf8 Breg[4][8];
  f32x4 bias4[4];
  #pragma unroll
  for (int n=0;n<4;n++){
    int colp = wave*64 + n*16 + mL;
    bias4[n] = *reinterpret_cast<const f32x4*>(bb + n*128 + wave*16 + quad*4);
    #pragma unroll
    for (int ks=0;ks<8;ks++){
      int k = ks*32 + kb;
      const u16* p = (k<128) ? (Wih + colp*128 + k) : (Whh + colp*128 + (k-128));
      Breg[n][ks] = *reinterpret_cast<const bf8*>(p);
      asm volatile("" : "+v"(Breg[n][ks]));
    }
  }

  if (tid<256){
    int r = tid>>4, c = tid&15;
    *reinterpret_cast<i32x4*>(&xh[r*XROW + 256 + c*8]) = (i32x4){0,0,0,0};
  }

  const int srow = tid>>5, schunk = tid&31;
  float cst[4] = {0.f,0.f,0.f,0.f};
  float hst[4] = {0.f,0.f,0.f,0.f};

  __syncthreads();

  {
    int tok = toks[srow*T_ + (dir ? (T_-1) : 0)];
    f32x4 xv = *reinterpret_cast<const f32x4*>(emb + tok*128 + schunk*4);
    s16x4 xp;
    #pragma unroll
    for (int i=0;i<4;i++) xp[i]=(short)f2bf(xv[i]);
    *reinterpret_cast<s16x4*>(&xh[srow*XROW + schunk*4]) = xp;
  }
  f32x4 xv1, xv2;
  {
    int tok1 = toks[srow*T_ + (dir ? (T_-2) : 1)];
    xv1 = *reinterpret_cast<const f32x4*>(emb + tok1*128 + schunk*4);
    int tok2 = toks[srow*T_ + (dir ? (T_-3) : 2)];
    xv2 = *reinterpret_cast<const f32x4*>(emb + tok2*128 + schunk*4);
  }
  __syncthreads();

  for (int t=0;t<T_;t++){
    const int cb = t&1, nb2 = (t+1)&1;
    if (t+1 < T_){
      s16x4 xp;
      #pragma unroll
      for (int i=0;i<4;i++) xp[i]=(short)f2bf(xv1[i]);
      *reinterpret_cast<s16x4*>(&xh[srow*XROW + nb2*128 + schunk*4]) = xp;
    }
    xv1 = xv2;
    if (t+3 < T_){
      int tok = toks[srow*T_ + (dir ? (T_-4-t) : (t+3))];
      xv2 = *reinterpret_cast<const f32x4*>(emb + tok*128 + schunk*4);
    }

    f32x4 acc[4];
    #pragma unroll
    for (int i=0;i<4;i++) acc[i] = (f32x4){0.f,0.f,0.f,0.f};
    #pragma unroll
    for (int ks=0;ks<8;ks++){
      int k = ks*32 + kb;
      int off = (k<128) ? (cb*128 + k) : (256 + cb*128 + (k-128));
      bf8 b = *reinterpret_cast<const bf8*>(&xh[mL*XROW + off]);
      #pragma unroll
      for (int n=0;n<4;n++)
        acc[n] = __builtin_amdgcn_mfma_f32_16x16x32_bf16(Breg[n][ks], b, acc[n], 0,0,0);
    }

    s16x4 hp;
    #pragma unroll
    for (int i=0;i<4;i++){
      float gi_ = acc[0][i]+bias4[0][i];
      float gf_ = acc[1][i]+bias4[1][i];
      float gg_ = acc[2][i]+bias4[2][i];
      float go_ = acc[3][i]+bias4[3][i];
      float c = sigm(gf_)*cst[i] + sigm(gi_)*tanh_(gg_);
      float h = sigm(go_)*tanh_(c);
      cst[i]=c; hst[i]=h;
      hp[i] = (short)f2bf(h);
    }
    *reinterpret_cast<s16x4*>(&xh[mL*XROW + 256 + nb2*128 + wave*16 + quad*4]) = hp;
    bar_lds();
  }

  {
    const int ch = wave*16 + quad*4;
    const int gs = s0 + mL;
    s16x4 cp_, hp_;
    #pragma unroll
    for (int i=0;i<4;i++){ cp_[i]=(short)f2bf(cst[i]); hp_[i]=(short)f2bf(hst[i]); }
    *reinterpret_cast<s16x4*>(c_cat + gs*256 + dir*128 + ch) = cp_;
    *reinterpret_cast<s16x4*>(h_cat + gs*256 + dir*128 + ch) = hp_;
  }
}

// ---------------------------------------------------------------------------
// Stage 2: hidden = [relu(cc@Wc.T+bc) | relu(hc@Whr.T+bhr)], row 0 zeroed.
// ---------------------------------------------------------------------------
__global__ __launch_bounds__(256) void reduce_kernel(
    const u16* __restrict__ c_cat, const u16* __restrict__ h_cat,
    const u16* __restrict__ Wc, const float* __restrict__ bc,
    const u16* __restrict__ Whr, const float* __restrict__ bhr,
    float* __restrict__ hidf, u16* __restrict__ hidb)
{
  const int tid=threadIdx.x, wave=tid>>6, lane=tid&63;
  const int mL=lane&15, quad=lane>>4, kb=quad*8;
  const int m0 = blockIdx.x*64;
  const u16* A    = (wave<2) ? c_cat : h_cat;
  const u16* W    = (wave<2) ? Wc  : Whr;
  const float* bv = (wave<2) ? bc  : bhr;
  const int nb    = (wave&1)*64;
  const int obase = (wave<2) ? 0 : 128;

  f32x4 acc[4][4];
  #pragma unroll
  for (int mt=0;mt<4;mt++)
    #pragma unroll
    for (int nt=0;nt<4;nt++) acc[mt][nt] = (f32x4){0.f,0.f,0.f,0.f};

  #pragma unroll
  for (int ks=0;ks<8;ks++){
    int k = ks*32 + kb;
    bf8 bfr[4];
    #pragma unroll
    for (int nt=0;nt<4;nt++)
      bfr[nt] = *reinterpret_cast<const bf8*>(W + (nb+nt*16+mL)*256 + k);
    #pragma unroll
    for (int mt=0;mt<4;mt++){
      bf8 a = *reinterpret_cast<const bf8*>(A + (m0+mt*16+mL)*256 + k);
      #pragma unroll
      for (int nt=0;nt<4;nt++)
        acc[mt][nt] = __builtin_amdgcn_mfma_f32_16x16x32_bf16(a, bfr[nt], acc[mt][nt], 0,0,0);
    }
  }
  const int row0 = quad*4;
  float biasv[4];
  #pragma unroll
  for (int nt=0;nt<4;nt++) biasv[nt] = bv[nb+nt*16+mL];
  #pragma unroll
  for (int mt=0;mt<4;mt++){
    #pragma unroll
    for (int nt=0;nt<4;nt++){
      int col = obase + nb + nt*16 + mL;
      #pragma unroll
      for (int i=0;i<4;i++){
        int r = m0 + mt*16 + row0 + i;
        float v = fmaxf(acc[mt][nt][i] + biasv[nt], 0.f);
        hidf[(r+1)*256 + col] = v;
        hidb[(r+1)*256 + col] = f2bf(v);
      }
    }
  }
  if (blockIdx.x==0 && tid<64){
    #pragma unroll
    for (int j=0;j<4;j++){ hidf[tid*4+j] = 0.f; hidb[tid*4+j] = 0; }
  }
}

// ---------------------------------------------------------------------------
// Stage 3 (x4): gi = hidden@Wi.T + bi, gh = hidden@Wh.T + bh  (bf16 tables)
// M-tile 16 -> 582 blocks (was 294) for occupancy/latency hiding.
// ---------------------------------------------------------------------------
__global__ __launch_bounds__(256) void gates_gemm_kernel(
    const u16* __restrict__ hidb,
    const u16* __restrict__ Wi, const u16* __restrict__ Wh,
    const float* __restrict__ bi, const float* __restrict__ bh,
    u16* __restrict__ gi, u16* __restrict__ gh)
{
  const int tid=threadIdx.x, wave=tid>>6, lane=tid&63;
  const int mL=lane&15, quad=lane>>4, kb=quad*8;
  const int m0 = blockIdx.x*16;
  const int n0 = blockIdx.y*256 + wave*64;
  const bool isI = (n0 < 768);
  const u16* W    = isI ? Wi : Wh;
  const float* bv = isI ? bi : bh;
  u16* out        = isI ? gi : gh;
  const int nbc   = isI ? n0 : (n0-768);

  const int arow = min(m0+mL, NR-1);

  f32x4 acc[4];
  #pragma unroll
  for (int nt=0;nt<4;nt++) acc[nt] = (f32x4){0.f,0.f,0.f,0.f};

  #pragma unroll
  for (int ks=0;ks<8;ks++){
    int k = ks*32 + kb;
    bf8 bfr[4];
    #pragma unroll
    for (int nt=0;nt<4;nt++)
      bfr[nt] = *reinterpret_cast<const bf8*>(W + (nbc+nt*16+mL)*256 + k);
    bf8 a = *reinterpret_cast<const bf8*>(hidb + arow*256 + k);
    #pragma unroll
    for (int nt=0;nt<4;nt++)
      acc[nt] = __builtin_amdgcn_mfma_f32_16x16x32_bf16(a, bfr[nt], acc[nt], 0,0,0);
  }
  const int row0 = quad*4;
  #pragma unroll
  for (int nt=0;nt<4;nt++){
    float biasv = bv[nbc+nt*16+mL];
    #pragma unroll
    for (int i=0;i<4;i++){
      int r = m0 + row0 + i;
      if (r < NR)
        out[r*768 + nbc + nt*16 + mL] = f2bf(acc[nt][i] + biasv);
    }
  }
}

// ---------------------------------------------------------------------------
// Stage 4 (x4): round-6 structure (1537 blocks x 8 waves, wave strides
// partners by 8, LDS cross-wave reduce) + manual 1-deep software pipeline:
// next iteration's 7 loads issued before current compute (clamped index,
// duplicate tail loads are side-effect-free).
// ---------------------------------------------------------------------------
__global__ __launch_bounds__(512) void pair_kernel(
    const u16* __restrict__ gi, const u16* __restrict__ gh,
    const float* __restrict__ hin,
    float* __restrict__ hout, u16* __restrict__ bout, float* __restrict__ dout,
    const int2* __restrict__ ent, const int* __restrict__ cnt)
{
  const int r = blockIdx.x;
  const int tid = threadIdx.x, wave = tid>>6, lane = tid&63;
  __shared__ float part[8][260];
  __shared__ float ssum[4];
  if (r==0){
    if (tid<256){
      hout[tid]=0.f; bout[tid]=0;
      if (dout) dout[tid]=0.f;
    }
    return;
  }
  const int rr = r-1;
  const int n  = cnt[rr];              // padded to multiple of 4 (sentinels -> 0)
  const int2* e = ent + rr*S_;
  const int ch0 = lane*4;

  float a0=0.f, a1=0.f, a2=0.f, a3=0.f;
  int k = wave;
  if (k < n){
    // prologue: load iteration k
    int2 E = e[k];
    const u16* gx = gi + E.x*768 + ch0;
    const u16* gy = gh + E.y*768 + ch0;
    s16x4 vi0 = *reinterpret_cast<const s16x4*>(gx);
    s16x4 vi1 = *reinterpret_cast<const s16x4*>(gx+256);
    s16x4 vi2 = *reinterpret_cast<const s16x4*>(gx+512);
    s16x4 vh0 = *reinterpret_cast<const s16x4*>(gy);
    s16x4 vh1 = *reinterpret_cast<const s16x4*>(gy+256);
    s16x4 vh2 = *reinterpret_cast<const s16x4*>(gy+512);
    f32x4 hv  = *reinterpret_cast<const f32x4*>(hin + E.y*256 + ch0);
    while (true){
      const int k2 = k + 8;
      const bool more = (k2 < n);
      const int kc = more ? k2 : k;     // clamp: duplicate load, never used
      // issue next iteration's loads BEFORE current compute
      int2 E2 = e[kc];
      const u16* gx2 = gi + E2.x*768 + ch0;
      const u16* gy2 = gh + E2.y*768 + ch0;
      s16x4 wi0 = *reinterpret_cast<const s16x4*>(gx2);
      s16x4 wi1 = *reinterpret_cast<const s16x4*>(gx2+256);
      s16x4 wi2 = *reinterpret_cast<const s16x4*>(gx2+512);
      s16x4 wh0 = *reinterpret_cast<const s16x4*>(gy2);
      s16x4 wh1 = *reinterpret_cast<const s16x4*>(gy2+256);
      s16x4 wh2 = *reinterpret_cast<const s16x4*>(gy2+512);
      f32x4 hv2 = *reinterpret_cast<const f32x4*>(hin + E2.y*256 + ch0);
      // compute current
      #pragma unroll
      for (int i=0;i<4;i++){
        float rg = sigm(bf2f((u16)vi0[i]) + bf2f((u16)vh0[i]));
        float zg = sigm(bf2f((u16)vi1[i]) + bf2f((u16)vh1[i]));
        float ng = tanh_(bf2f((u16)vi2[i]) + rg*bf2f((u16)vh2[i]));
        float o  = (1.f-zg)*ng + zg*hv[i];
        if (i==0) a0 += o; else if (i==1) a1 += o; else if (i==2) a2 += o; else a3 += o;
      }
      if (!more) break;
      vi0=wi0; vi1=wi1; vi2=wi2; vh0=wh0; vh1=wh1; vh2=wh2; hv=hv2;
      k = k2;
    }
  }
  *reinterpret_cast<f32x4*>(&part[wave][ch0]) = (f32x4){a0,a1,a2,a3};
  __syncthreads();

  if (tid < 256){
    float tot = part[0][tid] + part[1][tid] + part[2][tid] + part[3][tid]
              + part[4][tid] + part[5][tid] + part[6][tid] + part[7][tid];
    part[0][tid] = tot;                 // stash for epilogue
    float sq = tot*tot;
    #pragma unroll
    for (int off=32; off>0; off>>=1) sq += __shfl_xor(sq, off, 64);
    if (lane==0) ssum[wave] = sq;
  }
  __syncthreads();
  if (tid < 256){
    float tot = part[0][tid];
    float v  = sqrtf(ssum[0]+ssum[1]+ssum[2]+ssum[3]);
    float sc = (v + 0.25f)*__builtin_amdgcn_rcpf(v + 1.f);
    float nv = hin[r*256 + tid] + tot*sc;
    hout[r*256 + tid] = nv;
    bout[r*256 + tid] = f2bf(nv);
    if (dout) dout[r*256 + tid] = nv;
  }
}

// ---------------------------------------------------------------------------
extern "C" void kernel_launch(void* const* d_in, const int* in_sizes, int n_in,
                              void* d_out, int out_size, void* d_ws, size_t ws_size,
                              hipStream_t stream)
{
  const int*   enc  = (const int*)  d_in[0];
  const int*   spar = (const int*)  d_in[1];
  const int*   schi = (const int*)  d_in[2];
  const float* mask = (const float*)d_in[3];
  const float* emb  = (const float*)d_in[4];
  const float* WihF = (const float*)d_in[5];
  const float* WhhF = (const float*)d_in[6];
  const float* bF   = (const float*)d_in[7];
  const float* WihB = (const float*)d_in[8];
  const float* WhhB = (const float*)d_in[9];
  const float* bB   = (const float*)d_in[10];
  const float* Wc   = (const float*)d_in[11];
  const float* bc   = (const float*)d_in[12];
  const float* Whr  = (const float*)d_in[13];
  const float* bhr  = (const float*)d_in[14];
  const float* WiCP = (const float*)d_in[15];
  const float* WhCP = (const float*)d_in[16];
  const float* biCP = (const float*)d_in[17];
  const float* bhCP = (const float*)d_in[18];
  const float* WiPC = (const float*)d_in[19];
  const float* WhPC = (const float*)d_in[20];
  const float* biPC = (const float*)d_in[21];
  const float* bhPC = (const float*)d_in[22];

  // workspace layout (~14.8 MB); hf/gi/gh have NR+1 rows (sentinel row ZR)
  char* ws = (char*)d_ws;
  u16*   c_cat = (u16*)  (ws + 0);          // 1536*256 bf16
  u16*   h_cat = (u16*)  (ws + 786432);
  float* hf0   = (float*)(ws + 1572864);    // 1538*256 f32
  float* hf1   = (float*)(ws + 3148800);    // 1538*256 f32
  u16*   hb    = (u16*)  (ws + 4724736);    // 1537*256 bf16
  u16*   gi    = (u16*)  (ws + 5511680);    // 1538*768 bf16
  u16*   gh    = (u16*)  (ws + 7874048);
  u16*   wbf   = (u16*)  (ws + 10236416);   // bf16 weights (1114112 elems)
  int2*  ent0  = (int2*) (ws + 12464640);   // 1536*96 int2
  int2*  ent1  = (int2*) (ws + 13644288);
  int*   cnt0  = (int*)  (ws + 14823936);
  int*   cnt1  = (int*)  (ws + 14830080);
  float* out   = (float*)d_out;

  u16* bWihF = wbf + 0;
  u16* bWhhF = wbf + 65536;
  u16* bWihB = wbf + 131072;
  u16* bWhhB = wbf + 196608;
  u16* bWc   = wbf + 262144;
  u16* bWhr  = wbf + 294912;
  u16* bWiCP = wbf + 327680;
  u16* bWhCP = wbf + 524288;
  u16* bWiPC = wbf + 720896;
  u16* bWhPC = wbf + 917504;

  CvtArgs ca;
  ca.s[0]=WihF; ca.s[1]=WhhF; ca.s[2]=WihB; ca.s[3]=WhhB;
  ca.s[4]=Wc;   ca.s[5]=Whr;
  ca.s[6]=WiCP; ca.s[7]=WhCP; ca.s[8]=WiPC; ca.s[9]=WhPC;
  ca.d[0]=bWihF; ca.d[1]=bWhhF; ca.d[2]=bWihB; ca.d[3]=bWhhB;
  ca.d[4]=bWc;   ca.d[5]=bWhr;
  ca.d[6]=bWiCP; ca.d[7]=bWhCP; ca.d[8]=bWiPC; ca.d[9]=bWhPC;
  prep_kernel<<<dim3(1088+NSEQ+1), dim3(256), 0, stream>>>(
      ca, spar, schi, mask, ent0, cnt0, ent1, cnt1, gi, gh, hf0, hf1);

  lstm_kernel<<<dim3(96,2), dim3(512), 0, stream>>>(
      enc, emb, bWihF,bWhhF,bF, bWihB,bWhhB,bB, c_cat, h_cat);
  reduce_kernel<<<dim3(24), dim3(256), 0, stream>>>(
      c_cat,h_cat, bWc,bc,bWhr,bhr, hf0,hb);

  float* hfb[2] = {hf0,hf1};
  int cur = 0;
  for (int it=0; it<4; it++){
    const u16* Wi   = (it<2)?bWiCP:bWiPC;
    const u16* Wh   = (it<2)?bWhCP:bWhPC;
    const float* bi = (it<2)?biCP:biPC;
    const float* bh = (it<2)?bhCP:bhPC;
    int nxt = cur^1;
    gates_gemm_kernel<<<dim3(97,6), dim3(256), 0, stream>>>(
        hb, Wi,Wh,bi,bh, gi,gh);
    pair_kernel<<<dim3(NR), dim3(512), 0, stream>>>(
        gi,gh, hfb[cur], hfb[nxt], hb,
        (it==3)?out:(float*)nullptr,
        (it<2)?ent0:ent1, (it<2)?cnt0:cnt1);
    cur = nxt;
  }
}